// Round 4
// baseline (4621.372 us; speedup 1.0000x reference)
//
#include <hip/hip_runtime.h>
#include <math.h>

#define NB 16
#define NT 12
#define NN 2048
#define NH 16
#define NK 20

#define RPB 16    // rows per block (shared by all 4 waves)
#define CCAP 64

static __device__ __forceinline__ unsigned long long shflxor64(unsigned long long v, int m) {
  unsigned lo = (unsigned)v, hi = (unsigned)(v >> 32);
  lo = (unsigned)__shfl_xor((int)lo, m, 64);
  hi = (unsigned)__shfl_xor((int)hi, m, 64);
  return ((unsigned long long)hi << 32) | lo;
}

// one exact FMA order used by pass A, pass B, gather, and fallback:
static __device__ __forceinline__ float dotQ(const float* q, const float4& e0,
                                             const float4& e1, const float4& e2,
                                             const float4& e3) {
  float a = 0.0f;
  a = __fmaf_rn(q[0], e0.x, a);  a = __fmaf_rn(q[1], e0.y, a);
  a = __fmaf_rn(q[2], e0.z, a);  a = __fmaf_rn(q[3], e0.w, a);
  a = __fmaf_rn(q[4], e1.x, a);  a = __fmaf_rn(q[5], e1.y, a);
  a = __fmaf_rn(q[6], e1.z, a);  a = __fmaf_rn(q[7], e1.w, a);
  a = __fmaf_rn(q[8], e2.x, a);  a = __fmaf_rn(q[9], e2.y, a);
  a = __fmaf_rn(q[10], e2.z, a); a = __fmaf_rn(q[11], e2.w, a);
  a = __fmaf_rn(q[12], e3.x, a); a = __fmaf_rn(q[13], e3.y, a);
  a = __fmaf_rn(q[14], e3.z, a); a = __fmaf_rn(q[15], e3.w, a);
  return a;
}

// ---- kernel 0: state mean + 16-dim tanh embedding -------------------------
__global__ void k_emb(const float* __restrict__ x, const float* __restrict__ W,
                      const float* __restrict__ bias, float* __restrict__ emb) {
  int id = blockIdx.x * blockDim.x + threadIdx.x;
  if (id >= NB * NN) return;
  int b = id >> 11, n = id & (NN - 1);
  const float* xp = x + ((size_t)b * NT) * NN + n;
  float s = 0.0f;
#pragma unroll
  for (int t = 0; t < NT; ++t) s += xp[(size_t)t * NN];
  s = s / 12.0f;
  float* e = emb + (size_t)id * NH;
#pragma unroll
  for (int h = 0; h < NH; ++h) {
    float arg = __fadd_rn(__fmul_rn(s, W[h]), bias[h]);
    e[h] = (float)tanh((double)arg);
  }
}

// ---- kernel 1: A_physical row sums -> a / (sum + 1e-8) --------------------
__global__ void k_rowsum(const float* __restrict__ A, const float* __restrict__ alpha,
                         float* __restrict__ aInv) {
  int gw = (blockIdx.x * blockDim.x + threadIdx.x) >> 6;
  int lane = threadIdx.x & 63;
  if (gw >= NN) return;
  const float* row = A + (size_t)gw * NN;
  float s = 0.0f;
#pragma unroll
  for (int j = 0; j < NN / 64; ++j) s += row[lane + 64 * j];
#pragma unroll
  for (int off = 32; off; off >>= 1) s += __shfl_xor(s, off, 64);
  if (lane == 0) {
    float a = 1.0f / (1.0f + expf(-alpha[0]));
    aInv[gw] = a / (s + 1e-8f);
  }
}

// ---- kernel 2: two-pass streaming top-20 + softmax ------------------------
// Block = 16 rows; waves split the NODE range (512 nodes each) -> grid 2048.
__global__ __launch_bounds__(256) void k_topk(
    const float* __restrict__ emb, const float* __restrict__ Ap,
    const float* __restrict__ aInv, const float* __restrict__ alpha,
    unsigned short* __restrict__ fixIdx, float* __restrict__ fixVal) {
  __shared__ unsigned short candIdx[RPB][CCAP];   // 2 KB
  __shared__ int candCnt[RPB];
  __shared__ float thW[4][RPB];
  __shared__ float thC[RPB];
  __shared__ unsigned long long fsel[4][NK];

  const int tid = threadIdx.x;
  const int lane = tid & 63;
  const int wv = tid >> 6;
  const int b = blockIdx.x >> 7;          // 128 blocks per batch
  const int rbase = (blockIdx.x & 127) * RPB;
  const float* embB = emb + (size_t)b * NN * NH;

  if (tid < RPB) candCnt[tid] = 0;

  // ---- pass A: per-lane running max; lane owns 4 consecutive nodes/tile ----
  float rmax[RPB];
#pragma unroll
  for (int r = 0; r < RPB; ++r) rmax[r] = -1.0f;

#pragma unroll 1
  for (int et = 0; et < 2; ++et) {
    asm volatile("" ::: "memory");  // block LICM of q loads (spill guard)
    const float* p0 = embB + (size_t)(wv * 512 + et * 256 + lane * 4) * NH;
    float4 a0 = *(const float4*)(p0 + 0),  a1 = *(const float4*)(p0 + 4),
           a2 = *(const float4*)(p0 + 8),  a3 = *(const float4*)(p0 + 12);
    float4 b0 = *(const float4*)(p0 + 16), b1 = *(const float4*)(p0 + 20),
           b2 = *(const float4*)(p0 + 24), b3 = *(const float4*)(p0 + 28);
    float4 c0 = *(const float4*)(p0 + 32), c1 = *(const float4*)(p0 + 36),
           c2 = *(const float4*)(p0 + 40), c3 = *(const float4*)(p0 + 44);
    float4 d0 = *(const float4*)(p0 + 48), d1 = *(const float4*)(p0 + 52),
           d2 = *(const float4*)(p0 + 56), d3 = *(const float4*)(p0 + 60);
#pragma unroll
    for (int r = 0; r < RPB; ++r) {
      const float* qp = embB + (size_t)(rbase + r) * NH;
      float qv[16];
#pragma unroll
      for (int h = 0; h < 16; ++h) qv[h] = qp[h];
      float v0 = fmaxf(dotQ(qv, a0, a1, a2, a3), 0.0f);
      float v1 = fmaxf(dotQ(qv, b0, b1, b2, b3), 0.0f);
      float v2 = fmaxf(dotQ(qv, c0, c1, c2, c3), 0.0f);
      float v3 = fmaxf(dotQ(qv, d0, d1, d2, d3), 0.0f);
      rmax[r] = fmaxf(rmax[r], fmaxf(fmaxf(v0, v1), fmaxf(v2, v3)));
    }
  }

  // ---- per-wave 20th-largest lane-max (valid lower bound on v20) ----
#pragma unroll 1
  for (int r = 0; r < RPB; ++r) {
    float v = rmax[r];
#pragma unroll
    for (int k = 2; k <= 64; k <<= 1) {
#pragma unroll
      for (int m = k >> 1; m > 0; m >>= 1) {
        float o = __shfl_xor(v, m, 64);
        bool up = (lane & k) != 0;
        bool takeMax = ((lane & m) == 0) ^ up;
        v = takeMax ? fmaxf(v, o) : fminf(v, o);
      }
    }
    float t19 = __shfl(v, 19, 64);
    if (lane == 0) thW[wv][r] = t19;
  }
  __syncthreads();
  if (tid < RPB)
    thC[tid] = fmaxf(fmaxf(thW[0][tid], thW[1][tid]),
                     fmaxf(thW[2][tid], thW[3][tid]));
  __syncthreads();

  // ---- pass B: identical sweep, compact candidate indices (block-level) ----
#pragma unroll 1
  for (int et = 0; et < 2; ++et) {
    asm volatile("" ::: "memory");
    const int nb0 = wv * 512 + et * 256 + lane * 4;
    const float* p0 = embB + (size_t)nb0 * NH;
    float4 a0 = *(const float4*)(p0 + 0),  a1 = *(const float4*)(p0 + 4),
           a2 = *(const float4*)(p0 + 8),  a3 = *(const float4*)(p0 + 12);
    float4 b0 = *(const float4*)(p0 + 16), b1 = *(const float4*)(p0 + 20),
           b2 = *(const float4*)(p0 + 24), b3 = *(const float4*)(p0 + 28);
    float4 c0 = *(const float4*)(p0 + 32), c1 = *(const float4*)(p0 + 36),
           c2 = *(const float4*)(p0 + 40), c3 = *(const float4*)(p0 + 44);
    float4 d0 = *(const float4*)(p0 + 48), d1 = *(const float4*)(p0 + 52),
           d2 = *(const float4*)(p0 + 56), d3 = *(const float4*)(p0 + 60);
#pragma unroll
    for (int r = 0; r < RPB; ++r) {
      const float* qp = embB + (size_t)(rbase + r) * NH;
      float qv[16];
#pragma unroll
      for (int h = 0; h < 16; ++h) qv[h] = qp[h];
      float v0 = fmaxf(dotQ(qv, a0, a1, a2, a3), 0.0f);
      float v1 = fmaxf(dotQ(qv, b0, b1, b2, b3), 0.0f);
      float v2 = fmaxf(dotQ(qv, c0, c1, c2, c3), 0.0f);
      float v3 = fmaxf(dotQ(qv, d0, d1, d2, d3), 0.0f);
      float t = thC[r];
      if (v0 >= t) { int s = atomicAdd(&candCnt[r], 1); if (s < CCAP) candIdx[r][s] = (unsigned short)(nb0 + 0); }
      if (v1 >= t) { int s = atomicAdd(&candCnt[r], 1); if (s < CCAP) candIdx[r][s] = (unsigned short)(nb0 + 1); }
      if (v2 >= t) { int s = atomicAdd(&candCnt[r], 1); if (s < CCAP) candIdx[r][s] = (unsigned short)(nb0 + 2); }
      if (v3 >= t) { int s = atomicAdd(&candCnt[r], 1); if (s < CCAP) candIdx[r][s] = (unsigned short)(nb0 + 3); }
    }
  }
  __syncthreads();

  // ---- final: wave wv owns rows [wv*4, wv*4+4) ----
  float a_sig = 1.0f / (1.0f + expf(-alpha[0]));
  float oma = 1.0f - a_sig;

#pragma unroll 1
  for (int rr = 0; rr < 4; ++rr) {
    const int r = wv * 4 + rr;
    const int row = rbase + r;
    const float* qp = embB + (size_t)row * NH;
    float qv[16];
#pragma unroll
    for (int h = 0; h < 16; ++h) qv[h] = qp[h];

    int cnt = __builtin_amdgcn_readfirstlane(candCnt[r]);
    unsigned long long key = 0ull;
    if (cnt <= CCAP) {
      if (lane < cnt) {
        unsigned ci = candIdx[r][lane];
        const float* ep = embB + (size_t)ci * NH;
        float4 e0 = *(const float4*)(ep + 0), e1 = *(const float4*)(ep + 4),
               e2 = *(const float4*)(ep + 8), e3 = *(const float4*)(ep + 12);
        float dd = fmaxf(dotQ(qv, e0, e1, e2, e3), 0.0f);
        key = ((unsigned long long)__float_as_uint(dd) << 32) | (unsigned)(~ci);
      }
#pragma unroll
      for (int k = 2; k <= 64; k <<= 1) {
#pragma unroll
        for (int m = k >> 1; m > 0; m >>= 1) {
          unsigned long long o = shflxor64(key, m);
          bool up = (lane & k) != 0;
          bool takeMax = ((lane & m) == 0) ^ up;
          key = (takeMax == (key > o)) ? key : o;
        }
      }
    } else {
      // rare exact fallback (flat/tied rows): 20x wave argmax with recompute
      unsigned taken = 0u;
#pragma unroll 1
      for (int sel = 0; sel < NK; ++sel) {
        float bv = -1.0f;
        int bs = 0;
#pragma unroll 1
        for (int s = 0; s < 32; ++s) {
          const float* ep = embB + (size_t)(s * 64 + lane) * NH;
          float4 e0 = *(const float4*)(ep + 0), e1 = *(const float4*)(ep + 4),
                 e2 = *(const float4*)(ep + 8), e3 = *(const float4*)(ep + 12);
          float dd = fmaxf(dotQ(qv, e0, e1, e2, e3), 0.0f);
          bool ok = ((taken >> s) & 1u) == 0u;
          bool bet = ok && (dd > bv);
          bv = bet ? dd : bv;
          bs = bet ? s : bs;
        }
        unsigned idx = (unsigned)(bs * 64 + lane);
        unsigned long long kk = ((unsigned long long)__float_as_uint(bv) << 32) | (unsigned)(~idx);
#pragma unroll
        for (int off = 32; off; off >>= 1) {
          unsigned long long o = shflxor64(kk, off);
          kk = (o > kk) ? o : kk;
        }
        unsigned wi = ~(unsigned)kk;
        if ((wi & 63u) == (unsigned)lane) taken |= (1u << (wi >> 6));
        if (lane == 0) fsel[wv][sel] = kk;
      }
      asm volatile("s_waitcnt lgkmcnt(0)" ::: "memory");
      key = (lane < NK) ? fsel[wv][lane] : 0ull;
    }

    // softmax over selected (desc-sorted; lanes 0..19 hold top-20)
    int kl = (cnt < NK) ? cnt : NK;   // cnt >= 20 by construction; defensive
    float vs = __uint_as_float((unsigned)(key >> 32));
    float vmax = __shfl(vs, 0, 64);
    float ex = (lane < kl) ? expf(vs - vmax) : 0.0f;
    float ssum = ex;
#pragma unroll
    for (int off = 32; off; off >>= 1) ssum += __shfl_xor(ssum, off, 64);
    if (lane < kl) {
      float w = ex / ssum;
      unsigned mi = ~(unsigned)key;
      float p = Ap[(size_t)row * NN + mi];
      size_t o20 = ((size_t)b * NN + row) * NK + lane;
      fixVal[o20] = __fadd_rn(__fmul_rn(p, aInv[row]), __fmul_rn(oma, w));
      fixIdx[o20] = (unsigned short)mi;
    }
  }
}

// ---- kernel 3: pure streaming output write --------------------------------
__global__ __launch_bounds__(256, 6) void k_out(
    const float* __restrict__ Ap, const float* __restrict__ aInv,
    const unsigned short* __restrict__ fixIdx, const float* __restrict__ fixVal,
    float* __restrict__ out) {
  const int tid = threadIdx.x;
  const int lane = tid & 63;
  const int q = tid >> 6;
  const int n = blockIdx.x;

  float ai = aInv[n];
  const float4* pr = (const float4*)(Ap + (size_t)n * NN);
  float4 o[8];
#pragma unroll
  for (int f = 0; f < 8; ++f) {
    float4 p = pr[lane + 64 * f];
    o[f].x = __fmul_rn(p.x, ai);
    o[f].y = __fmul_rn(p.y, ai);
    o[f].z = __fmul_rn(p.z, ai);
    o[f].w = __fmul_rn(p.w, ai);
  }

  unsigned short ii[4];
  float vv[4];
#pragma unroll
  for (int i = 0; i < 4; ++i) {
    int bb = q * 4 + i;
    if (lane < NK) {
      size_t o20 = ((size_t)bb * NN + n) * NK + lane;
      ii[i] = fixIdx[o20];
      vv[i] = fixVal[o20];
    }
  }

#pragma unroll
  for (int i = 0; i < 4; ++i) {
    int bb = q * 4 + i;
    float4* orow = (float4*)(out + ((size_t)bb * NN + n) * NN);
#pragma unroll
    for (int f = 0; f < 8; ++f) orow[lane + 64 * f] = o[f];
  }
  asm volatile("s_waitcnt vmcnt(0)" ::: "memory");
#pragma unroll
  for (int i = 0; i < 4; ++i) {
    if (lane < NK) {
      int bb = q * 4 + i;
      out[((size_t)bb * NN + n) * NN + (unsigned)ii[i]] = vv[i];
    }
  }
}

extern "C" void kernel_launch(void* const* d_in, const int* in_sizes, int n_in,
                              void* d_out, int out_size, void* d_ws, size_t ws_size,
                              hipStream_t stream) {
  const float* x = (const float*)d_in[0];
  const float* Ap = (const float*)d_in[1];
  const float* W = (const float*)d_in[2];
  const float* bb = (const float*)d_in[3];
  const float* alpha = (const float*)d_in[4];
  float* out = (float*)d_out;

  float* emb = (float*)d_ws;                                  // 2 MB
  float* aInv = emb + (size_t)NB * NN * NH;                   // 8 KB
  float* fixVal = aInv + NN;                                  // 2.62 MB
  unsigned short* fixIdx = (unsigned short*)(fixVal + (size_t)NB * NN * NK);  // 1.31 MB

  hipLaunchKernelGGL(k_emb, dim3((NB * NN + 255) / 256), dim3(256), 0, stream,
                     x, W, bb, emb);
  hipLaunchKernelGGL(k_rowsum, dim3((NN * 64) / 256), dim3(256), 0, stream,
                     Ap, alpha, aInv);
  hipLaunchKernelGGL(k_topk, dim3(NB * NN / RPB), dim3(256), 0, stream,
                     emb, Ap, aInv, alpha, fixIdx, fixVal);
  hipLaunchKernelGGL(k_out, dim3(NN), dim3(256), 0, stream,
                     Ap, aInv, fixIdx, fixVal, out);
}

// Round 5
// 236.230 us; speedup vs baseline: 19.5630x; 19.5630x over previous
//
#include <hip/hip_runtime.h>
#include <math.h>

#define NB 16
#define NT 12
#define NN 2048
#define NH 16
#define NK 20

#define RPWV 4    // rows per wave; wave sweeps ALL 2048 nodes (lane-max over 32)
#define CCAP 64

static __device__ __forceinline__ unsigned long long shflxor64(unsigned long long v, int m) {
  unsigned lo = (unsigned)v, hi = (unsigned)(v >> 32);
  lo = (unsigned)__shfl_xor((int)lo, m, 64);
  hi = (unsigned)__shfl_xor((int)hi, m, 64);
  return ((unsigned long long)hi << 32) | lo;
}

static __device__ __forceinline__ float rfl(float v) {
  return __int_as_float(__builtin_amdgcn_readfirstlane(__float_as_int(v)));
}

// one exact FMA order everywhere (pass A == pass B == gather == fallback):
static __device__ __forceinline__ float dotQ(const float* q, const float4& e0,
                                             const float4& e1, const float4& e2,
                                             const float4& e3) {
  float a = 0.0f;
  a = __fmaf_rn(q[0], e0.x, a);  a = __fmaf_rn(q[1], e0.y, a);
  a = __fmaf_rn(q[2], e0.z, a);  a = __fmaf_rn(q[3], e0.w, a);
  a = __fmaf_rn(q[4], e1.x, a);  a = __fmaf_rn(q[5], e1.y, a);
  a = __fmaf_rn(q[6], e1.z, a);  a = __fmaf_rn(q[7], e1.w, a);
  a = __fmaf_rn(q[8], e2.x, a);  a = __fmaf_rn(q[9], e2.y, a);
  a = __fmaf_rn(q[10], e2.z, a); a = __fmaf_rn(q[11], e2.w, a);
  a = __fmaf_rn(q[12], e3.x, a); a = __fmaf_rn(q[13], e3.y, a);
  a = __fmaf_rn(q[14], e3.z, a); a = __fmaf_rn(q[15], e3.w, a);
  return a;
}

// ---- kernel 0: state mean + 16-dim tanh embedding -------------------------
__global__ void k_emb(const float* __restrict__ x, const float* __restrict__ W,
                      const float* __restrict__ bias, float* __restrict__ emb) {
  int id = blockIdx.x * blockDim.x + threadIdx.x;
  if (id >= NB * NN) return;
  int b = id >> 11, n = id & (NN - 1);
  const float* xp = x + ((size_t)b * NT) * NN + n;
  float s = 0.0f;
#pragma unroll
  for (int t = 0; t < NT; ++t) s += xp[(size_t)t * NN];
  s = s / 12.0f;
  float* e = emb + (size_t)id * NH;
#pragma unroll
  for (int h = 0; h < NH; ++h) {
    float arg = __fadd_rn(__fmul_rn(s, W[h]), bias[h]);
    e[h] = (float)tanh((double)arg);
  }
}

// ---- kernel 1: A_physical row sums -> a / (sum + 1e-8) --------------------
__global__ void k_rowsum(const float* __restrict__ A, const float* __restrict__ alpha,
                         float* __restrict__ aInv) {
  int gw = (blockIdx.x * blockDim.x + threadIdx.x) >> 6;
  int lane = threadIdx.x & 63;
  if (gw >= NN) return;
  const float* row = A + (size_t)gw * NN;
  float s = 0.0f;
#pragma unroll
  for (int j = 0; j < NN / 64; ++j) s += row[lane + 64 * j];
#pragma unroll
  for (int off = 32; off; off >>= 1) s += __shfl_xor(s, off, 64);
  if (lane == 0) {
    float a = 1.0f / (1.0f + expf(-alpha[0]));
    aInv[gw] = a / (s + 1e-8f);
  }
}

// ---- kernel 2: two-pass streaming top-20 + softmax ------------------------
// Wave = 4 rows x all 2048 nodes. 8192 waves total -> 2048 blocks.
__global__ __launch_bounds__(256) void k_topk(
    const float* __restrict__ emb, const float* __restrict__ Ap,
    const float* __restrict__ aInv, const float* __restrict__ alpha,
    unsigned short* __restrict__ fixIdx, float* __restrict__ fixVal) {
  __shared__ unsigned short candIdx[4][RPWV][CCAP];   // 2 KB
  __shared__ int candCnt[4][RPWV];
  __shared__ unsigned long long fsel[4][NK];

  const int lane = threadIdx.x & 63;
  const int wv = threadIdx.x >> 6;
  const int gw = blockIdx.x * 4 + wv;     // wave id 0..8191
  const int b = gw >> 9;                  // 512 waves per batch
  const int rbase = (gw & 511) * RPWV;
  const float* embB = emb + (size_t)b * NN * NH;

  if (lane < RPWV) candCnt[wv][lane] = 0;
  asm volatile("s_waitcnt lgkmcnt(0)" ::: "memory");

  // ---- query embeddings -> wave-uniform scalars (SGPRs) ----
  float qs[RPWV][NH];
#pragma unroll
  for (int r = 0; r < RPWV; ++r) {
    const float* qp = embB + (size_t)(rbase + r) * NH;
    float4 t0 = *(const float4*)(qp + 0),  t1 = *(const float4*)(qp + 4),
           t2 = *(const float4*)(qp + 8),  t3 = *(const float4*)(qp + 12);
    qs[r][0] = rfl(t0.x);  qs[r][1] = rfl(t0.y);  qs[r][2] = rfl(t0.z);  qs[r][3] = rfl(t0.w);
    qs[r][4] = rfl(t1.x);  qs[r][5] = rfl(t1.y);  qs[r][6] = rfl(t1.z);  qs[r][7] = rfl(t1.w);
    qs[r][8] = rfl(t2.x);  qs[r][9] = rfl(t2.y);  qs[r][10] = rfl(t2.z); qs[r][11] = rfl(t2.w);
    qs[r][12] = rfl(t3.x); qs[r][13] = rfl(t3.y); qs[r][14] = rfl(t3.z); qs[r][15] = rfl(t3.w);
  }

  // ---- pass A: per-lane running max (lane owns 32 strided nodes) ----
  float rmax[RPWV];
#pragma unroll
  for (int r = 0; r < RPWV; ++r) rmax[r] = -1.0f;

#pragma unroll 1
  for (int et = 0; et < 8; ++et) {
#pragma unroll 2
    for (int j = 0; j < 4; ++j) {
      const float* ep = embB + (size_t)(et * 256 + j * 64 + lane) * NH;
      float4 e0 = *(const float4*)(ep + 0), e1 = *(const float4*)(ep + 4),
             e2 = *(const float4*)(ep + 8), e3 = *(const float4*)(ep + 12);
#pragma unroll
      for (int r = 0; r < RPWV; ++r) {
        float d = fmaxf(dotQ(qs[r], e0, e1, e2, e3), 0.0f);
        rmax[r] = fmaxf(rmax[r], d);
      }
    }
  }

  // ---- thresholds: th[r] = 20th largest of 64 lane-maxes (<= v20) ----
  float th[RPWV];
#pragma unroll
  for (int r = 0; r < RPWV; ++r) {
    float v = rmax[r];
#pragma unroll
    for (int k = 2; k <= 64; k <<= 1) {
#pragma unroll
      for (int m = k >> 1; m > 0; m >>= 1) {
        float o = __shfl_xor(v, m, 64);
        bool up = (lane & k) != 0;
        bool takeMax = ((lane & m) == 0) ^ up;
        v = takeMax ? fmaxf(v, o) : fminf(v, o);
      }
    }
    th[r] = rfl(__shfl(v, 19, 64));
  }

  // ---- pass B: identical sweep, compact candidate indices ----
#pragma unroll 1
  for (int et = 0; et < 8; ++et) {
#pragma unroll 2
    for (int j = 0; j < 4; ++j) {
      const int node = et * 256 + j * 64 + lane;
      const float* ep = embB + (size_t)node * NH;
      float4 e0 = *(const float4*)(ep + 0), e1 = *(const float4*)(ep + 4),
             e2 = *(const float4*)(ep + 8), e3 = *(const float4*)(ep + 12);
#pragma unroll
      for (int r = 0; r < RPWV; ++r) {
        float d = fmaxf(dotQ(qs[r], e0, e1, e2, e3), 0.0f);
        if (d >= th[r]) {
          int s = atomicAdd(&candCnt[wv][r], 1);
          if (s < CCAP) candIdx[wv][r][s] = (unsigned short)node;
        }
      }
    }
  }
  asm volatile("s_waitcnt lgkmcnt(0)" ::: "memory");

  // ---- per-row: gather candidates, exact sort, softmax, write fixes ----
  float a_sig = 1.0f / (1.0f + expf(-alpha[0]));
  float oma = 1.0f - a_sig;

#pragma unroll 1
  for (int r = 0; r < RPWV; ++r) {
    const int row = rbase + r;
    int cnt = __builtin_amdgcn_readfirstlane(candCnt[wv][r]);
    unsigned long long key = 0ull;
    if (cnt <= CCAP) {
      if (lane < cnt) {
        unsigned ci = candIdx[wv][r][lane];
        const float* ep = embB + (size_t)ci * NH;
        float4 e0 = *(const float4*)(ep + 0), e1 = *(const float4*)(ep + 4),
               e2 = *(const float4*)(ep + 8), e3 = *(const float4*)(ep + 12);
        float dd = fmaxf(dotQ(qs[r], e0, e1, e2, e3), 0.0f);
        key = ((unsigned long long)__float_as_uint(dd) << 32) | (unsigned)(~ci);
      }
#pragma unroll
      for (int k = 2; k <= 64; k <<= 1) {
#pragma unroll
        for (int m = k >> 1; m > 0; m >>= 1) {
          unsigned long long o = shflxor64(key, m);
          bool up = (lane & k) != 0;
          bool takeMax = ((lane & m) == 0) ^ up;
          key = (takeMax == (key > o)) ? key : o;
        }
      }
    } else {
      // rare exact fallback (flat/tied rows): 20x wave argmax with recompute
      unsigned taken = 0u;
#pragma unroll 1
      for (int sel = 0; sel < NK; ++sel) {
        float bv = -1.0f;
        int bs = 0;
#pragma unroll 1
        for (int s = 0; s < 32; ++s) {
          const float* ep = embB + (size_t)(s * 64 + lane) * NH;
          float4 e0 = *(const float4*)(ep + 0), e1 = *(const float4*)(ep + 4),
                 e2 = *(const float4*)(ep + 8), e3 = *(const float4*)(ep + 12);
          float dd = fmaxf(dotQ(qs[r], e0, e1, e2, e3), 0.0f);
          bool ok = ((taken >> s) & 1u) == 0u;
          bool bet = ok && (dd > bv);
          bv = bet ? dd : bv;
          bs = bet ? s : bs;
        }
        unsigned idx = (unsigned)(bs * 64 + lane);
        unsigned long long kk = ((unsigned long long)__float_as_uint(bv) << 32) | (unsigned)(~idx);
#pragma unroll
        for (int off = 32; off; off >>= 1) {
          unsigned long long o = shflxor64(kk, off);
          kk = (o > kk) ? o : kk;
        }
        unsigned wi = ~(unsigned)kk;
        if ((wi & 63u) == (unsigned)lane) taken |= (1u << (wi >> 6));
        if (lane == 0) fsel[wv][sel] = kk;
      }
      asm volatile("s_waitcnt lgkmcnt(0)" ::: "memory");
      key = (lane < NK) ? fsel[wv][lane] : 0ull;
    }

    // softmax over selected (desc-sorted; lanes 0..19 hold top-20)
    int kl = (cnt < NK) ? cnt : NK;   // cnt >= 20 by construction; defensive
    float vs = __uint_as_float((unsigned)(key >> 32));
    float vmax = __shfl(vs, 0, 64);
    float ex = (lane < kl) ? expf(vs - vmax) : 0.0f;
    float ssum = ex;
#pragma unroll
    for (int off = 32; off; off >>= 1) ssum += __shfl_xor(ssum, off, 64);
    if (lane < kl) {
      float w = ex / ssum;
      unsigned mi = ~(unsigned)key;
      float p = Ap[(size_t)row * NN + mi];
      size_t o20 = ((size_t)b * NN + row) * NK + lane;
      fixVal[o20] = __fadd_rn(__fmul_rn(p, aInv[row]), __fmul_rn(oma, w));
      fixIdx[o20] = (unsigned short)mi;
    }
  }
}

// ---- kernel 3: pure streaming output write --------------------------------
__global__ __launch_bounds__(256, 6) void k_out(
    const float* __restrict__ Ap, const float* __restrict__ aInv,
    const unsigned short* __restrict__ fixIdx, const float* __restrict__ fixVal,
    float* __restrict__ out) {
  const int tid = threadIdx.x;
  const int lane = tid & 63;
  const int q = tid >> 6;
  const int n = blockIdx.x;

  float ai = aInv[n];
  const float4* pr = (const float4*)(Ap + (size_t)n * NN);
  float4 o[8];
#pragma unroll
  for (int f = 0; f < 8; ++f) {
    float4 p = pr[lane + 64 * f];
    o[f].x = __fmul_rn(p.x, ai);
    o[f].y = __fmul_rn(p.y, ai);
    o[f].z = __fmul_rn(p.z, ai);
    o[f].w = __fmul_rn(p.w, ai);
  }

  unsigned short ii[4];
  float vv[4];
#pragma unroll
  for (int i = 0; i < 4; ++i) {
    int bb = q * 4 + i;
    if (lane < NK) {
      size_t o20 = ((size_t)bb * NN + n) * NK + lane;
      ii[i] = fixIdx[o20];
      vv[i] = fixVal[o20];
    }
  }

#pragma unroll
  for (int i = 0; i < 4; ++i) {
    int bb = q * 4 + i;
    float4* orow = (float4*)(out + ((size_t)bb * NN + n) * NN);
#pragma unroll
    for (int f = 0; f < 8; ++f) orow[lane + 64 * f] = o[f];
  }
  asm volatile("s_waitcnt vmcnt(0)" ::: "memory");
#pragma unroll
  for (int i = 0; i < 4; ++i) {
    if (lane < NK) {
      int bb = q * 4 + i;
      out[((size_t)bb * NN + n) * NN + (unsigned)ii[i]] = vv[i];
    }
  }
}

extern "C" void kernel_launch(void* const* d_in, const int* in_sizes, int n_in,
                              void* d_out, int out_size, void* d_ws, size_t ws_size,
                              hipStream_t stream) {
  const float* x = (const float*)d_in[0];
  const float* Ap = (const float*)d_in[1];
  const float* W = (const float*)d_in[2];
  const float* bb = (const float*)d_in[3];
  const float* alpha = (const float*)d_in[4];
  float* out = (float*)d_out;

  float* emb = (float*)d_ws;                                  // 2 MB
  float* aInv = emb + (size_t)NB * NN * NH;                   // 8 KB
  float* fixVal = aInv + NN;                                  // 2.62 MB
  unsigned short* fixIdx = (unsigned short*)(fixVal + (size_t)NB * NN * NK);  // 1.31 MB

  hipLaunchKernelGGL(k_emb, dim3((NB * NN + 255) / 256), dim3(256), 0, stream,
                     x, W, bb, emb);
  hipLaunchKernelGGL(k_rowsum, dim3((NN * 64) / 256), dim3(256), 0, stream,
                     Ap, alpha, aInv);
  hipLaunchKernelGGL(k_topk, dim3(NB * NN / (4 * RPWV)), dim3(256), 0, stream,
                     emb, Ap, aInv, alpha, fixIdx, fixVal);
  hipLaunchKernelGGL(k_out, dim3(NN), dim3(256), 0, stream,
                     Ap, aInv, fixIdx, fixVal, out);
}